// Round 2
// baseline (611.218 us; speedup 1.0000x reference)
//
#include <hip/hip_runtime.h>

#define BB 64
#define NN 512
#define FF 4
#define INC 64
#define HC 128
#define OUTC 16
#define KK (NN * FF)  // 2048

typedef short short8 __attribute__((ext_vector_type(8)));
typedef float f32x4 __attribute__((ext_vector_type(4)));

__device__ __forceinline__ unsigned short f2bf(float x) {
  union { float f; unsigned u; } v;
  v.f = x;
  unsigned r = v.u + 0x7fffu + ((v.u >> 16) & 1u);  // round-to-nearest-even
  return (unsigned short)(r >> 16);
}

__device__ __forceinline__ float silu_f(float x) {
  return x * (1.0f / (1.0f + __expf(-x)));
}

// ---------------------------------------------------------------------------
// Kernel 1: deg[b,i,f] = rsqrt(max(rowsum(adjhat), 1)), adjhat = adj w/ diag=1
// One wave per (b,i); lanes read float4 (all 4 edge types) coalesced.
// ---------------------------------------------------------------------------
__global__ __launch_bounds__(256) void deg_kernel(const float* __restrict__ adj,
                                                  float* __restrict__ deg) {
  int wave = blockIdx.x * 4 + (threadIdx.x >> 6);
  int lane = threadIdx.x & 63;
  int b = wave >> 9;
  int i = wave & (NN - 1);
  const float4* row = (const float4*)(adj) + (size_t)(b * NN + i) * NN;
  float4 s = make_float4(0.f, 0.f, 0.f, 0.f);
#pragma unroll
  for (int jj = 0; jj < NN / 64; ++jj) {
    float4 v = row[jj * 64 + lane];
    s.x += v.x; s.y += v.y; s.z += v.z; s.w += v.w;
  }
#pragma unroll
  for (int off = 32; off >= 1; off >>= 1) {
    s.x += __shfl_xor(s.x, off);
    s.y += __shfl_xor(s.y, off);
    s.z += __shfl_xor(s.z, off);
    s.w += __shfl_xor(s.w, off);
  }
  if (lane == 0) {
    float4 dg = row[i];  // adj[b,i,i,:]
    float4 o;
    o.x = rsqrtf(fmaxf(s.x - dg.x + 1.0f, 1.0f));
    o.y = rsqrtf(fmaxf(s.y - dg.y + 1.0f, 1.0f));
    o.z = rsqrtf(fmaxf(s.z - dg.z + 1.0f, 1.0f));
    o.w = rsqrtf(fmaxf(s.w - dg.w + 1.0f, 1.0f));
    ((float4*)deg)[b * NN + i] = o;
  }
}

// ---------------------------------------------------------------------------
// Kernel 2: Hs_T[b, c, j*4+f] = deg[b,j,f] * (xin[b,j,:] @ W[:,c])   (bf16)
// deg_j is folded HERE (and only here); agg's A-stage applies deg_i only.
// Stored transposed (c-major) so agg's B-fragments are contiguous in k.
// ---------------------------------------------------------------------------
__global__ __launch_bounds__(256) void lin_hs_kernel(
    const float* __restrict__ xin, const float* __restrict__ W,
    const float* __restrict__ deg, unsigned short* __restrict__ Hs, int CIN) {
  __shared__ float xt[16 * HC];  // up to 8 KB
  int b = blockIdx.y;
  int j0 = blockIdx.x * 16;
  int t = threadIdx.x;
  for (int idx = t; idx < 16 * CIN; idx += 256)
    xt[idx] = xin[(size_t)(b * NN + j0) * CIN + idx];
  __syncthreads();

  int c = t & (HC - 1);
  int gg = t >> 7;  // 0..1 -> 8 j-rows each
  float acc[8];
#pragma unroll
  for (int jj = 0; jj < 8; ++jj) acc[jj] = 0.f;
  const float* xrow = &xt[gg * 8 * CIN];
  for (int k = 0; k < CIN; k += 4) {
    float w0 = W[(k + 0) * HC + c];  // coalesced across lanes, L1/L2-hot
    float w1 = W[(k + 1) * HC + c];
    float w2 = W[(k + 2) * HC + c];
    float w3 = W[(k + 3) * HC + c];
#pragma unroll
    for (int jj = 0; jj < 8; ++jj) {
      float4 x4 = *(const float4*)&xrow[jj * CIN + k];  // LDS broadcast
      acc[jj] = fmaf(x4.x, w0, acc[jj]);
      acc[jj] = fmaf(x4.y, w1, acc[jj]);
      acc[jj] = fmaf(x4.z, w2, acc[jj]);
      acc[jj] = fmaf(x4.w, w3, acc[jj]);
    }
  }
#pragma unroll
  for (int jj = 0; jj < 8; ++jj) {
    int j = j0 + gg * 8 + jj;
    float4 d4 = ((const float4*)deg)[b * NN + j];
    ushort4 o;
    o.x = f2bf(acc[jj] * d4.x);
    o.y = f2bf(acc[jj] * d4.y);
    o.z = f2bf(acc[jj] * d4.z);
    o.w = f2bf(acc[jj] * d4.w);
    *(ushort4*)&Hs[(size_t)(b * HC + c) * KK + 4 * j] = o;  // 64 B/thread contiguous
  }
}

// ---------------------------------------------------------------------------
// Kernel 3: out[b,i,c] = silu(Sum_{j,f} A[i,(j,f)]*Hs[(j,f),c] + bias)*mask
// A-stage applies deg_i ONLY (deg_j lives in Hs). Diag substituted with 1.
// Block tile 64(i) x 128(c), BK=32. 4 waves, each 32x64 = 2x4 MFMA 16x16x32.
// mode 0: store hout.  mode 1: mean-pool into g (h2 never materialized).
// ---------------------------------------------------------------------------
__global__ __launch_bounds__(256) void agg_kernel(
    const float* __restrict__ adj, const float* __restrict__ deg,
    const unsigned short* __restrict__ Hs, const float* __restrict__ bias,
    const int* __restrict__ mask, float* __restrict__ hout,
    float* __restrict__ g, int mode) {
  __shared__ float smask[64];
  __shared__ float spool[HC];
  __shared__ unsigned short sA[64 * 40];     // rows padded 32->40 bf16
  __shared__ unsigned short sB[HC * 40];

  int b = blockIdx.y;
  int i0 = blockIdx.x * 64;
  int t = threadIdx.x;
  int lane = t & 63, w = t >> 6;
  int wm = w >> 1, wn = w & 1;

  if (t < 64) smask[t] = (float)mask[b * NN + i0 + t];
  if (t < HC) spool[t] = 0.f;
  __syncthreads();

  int arow = t >> 3, ac4 = t & 7;   // A staging: rows arow, arow+32; float4 ac4
  int brow = t >> 2, bc4 = t & 3;   // B staging: rows brow, brow+64
  const float4* adjb = (const float4*)(adj) + (size_t)(b * NN + i0) * NN;
  const unsigned short* HsB = Hs + (size_t)b * HC * KK;
  int lm = lane & 15, lk = lane >> 4;

  float4 dI0 = ((const float4*)deg)[b * NN + i0 + arow];
  float4 dI1 = ((const float4*)deg)[b * NN + i0 + arow + 32];

  f32x4 acc[2][4];
#pragma unroll
  for (int mt = 0; mt < 2; ++mt)
#pragma unroll
    for (int nt = 0; nt < 4; ++nt) acc[mt][nt] = (f32x4){0.f, 0.f, 0.f, 0.f};

  for (int k0 = 0; k0 < KK; k0 += 32) {
    int j0 = k0 >> 2;  // 8 j per step
    // --- A stage: adj fp32 -> self-loop sub -> scale by deg_i -> bf16 -> LDS
#pragma unroll
    for (int p = 0; p < 2; ++p) {
      int row = arow + p * 32;
      int ig = i0 + row;
      int j = j0 + ac4;
      float4 v = adjb[(size_t)row * NN + j];
      if (j == ig) v = make_float4(1.f, 1.f, 1.f, 1.f);  // self-loop
      float4 dI = p ? dI1 : dI0;
      ushort4 o;
      o.x = f2bf(v.x * dI.x);
      o.y = f2bf(v.y * dI.y);
      o.z = f2bf(v.z * dI.z);
      o.w = f2bf(v.w * dI.w);
      *(ushort4*)&sA[row * 40 + ac4 * 4] = o;
    }
    // --- B stage: Hs_T[c][k0..k0+32) bf16 -> LDS
#pragma unroll
    for (int p = 0; p < 2; ++p) {
      int row = brow + p * 64;
      float4 v = *(const float4*)&HsB[(size_t)row * KK + k0 + bc4 * 8];
      *(float4*)&sB[row * 40 + bc4 * 8] = v;
    }
    __syncthreads();

    short8 aF[2], bF[4];
#pragma unroll
    for (int mt = 0; mt < 2; ++mt)
      aF[mt] = *(const short8*)&sA[(wm * 32 + mt * 16 + lm) * 40 + lk * 8];
#pragma unroll
    for (int nt = 0; nt < 4; ++nt)
      bF[nt] = *(const short8*)&sB[(wn * 64 + nt * 16 + lm) * 40 + lk * 8];
#pragma unroll
    for (int mt = 0; mt < 2; ++mt)
#pragma unroll
      for (int nt = 0; nt < 4; ++nt)
        acc[mt][nt] = __builtin_amdgcn_mfma_f32_16x16x32_bf16(
            aF[mt], bF[nt], acc[mt][nt], 0, 0, 0);
    __syncthreads();
  }

  // --- epilogue: C/D layout row=(lane>>4)*4+r, col=lane&15 (verified m89/m91)
  if (mode == 0) {
#pragma unroll
    for (int mt = 0; mt < 2; ++mt) {
#pragma unroll
      for (int r = 0; r < 4; ++r) {
        int row = wm * 32 + mt * 16 + lk * 4 + r;
        float mk = smask[row];
        size_t base = (size_t)(b * NN + i0 + row) * HC;
#pragma unroll
        for (int nt = 0; nt < 4; ++nt) {
          int col = wn * 64 + nt * 16 + lm;
          hout[base + col] = silu_f(acc[mt][nt][r] + bias[col]) * mk;
        }
      }
    }
  } else {
    float psum[4] = {0.f, 0.f, 0.f, 0.f};
#pragma unroll
    for (int mt = 0; mt < 2; ++mt)
#pragma unroll
      for (int r = 0; r < 4; ++r) {
        int row = wm * 32 + mt * 16 + lk * 4 + r;
        float mk = smask[row];
#pragma unroll
        for (int nt = 0; nt < 4; ++nt) {
          int col = wn * 64 + nt * 16 + lm;
          psum[nt] += silu_f(acc[mt][nt][r] + bias[col]) * mk;
        }
      }
#pragma unroll
    for (int nt = 0; nt < 4; ++nt)
      atomicAdd(&spool[wn * 64 + nt * 16 + lm], psum[nt]);
    __syncthreads();
    if (t < HC) atomicAdd(&g[b * HC + t], spool[t] * (1.0f / (float)NN));
  }
}

// ---------------------------------------------------------------------------
// Kernel 4: g -> silu(g@Wl1+bl1) -> @Wl2+bl2. One block (128 thr) per batch.
// ---------------------------------------------------------------------------
__global__ __launch_bounds__(128) void mlp_kernel(
    const float* __restrict__ g, const float* __restrict__ Wl1,
    const float* __restrict__ bl1, const float* __restrict__ Wl2,
    const float* __restrict__ bl2, float* __restrict__ out) {
  __shared__ float sg[HC];
  __shared__ float sh[HC];
  int b = blockIdx.x, t = threadIdx.x;
  sg[t] = g[b * HC + t];
  __syncthreads();
  float acc = bl1[t];
  for (int k = 0; k < HC; ++k) acc = fmaf(sg[k], Wl1[k * HC + t], acc);
  sh[t] = silu_f(acc);
  __syncthreads();
  if (t < OUTC) {
    float a2 = bl2[t];
    for (int k = 0; k < HC; ++k) a2 = fmaf(sh[k], Wl2[k * OUTC + t], a2);
    out[b * OUTC + t] = a2;
  }
}

extern "C" void kernel_launch(void* const* d_in, const int* in_sizes, int n_in,
                              void* d_out, int out_size, void* d_ws,
                              size_t ws_size, hipStream_t stream) {
  const float* x   = (const float*)d_in[0];
  const float* adj = (const float*)d_in[1];
  const int*   msk = (const int*)d_in[2];
  const float* W0  = (const float*)d_in[3];
  const float* b0  = (const float*)d_in[4];
  const float* W1  = (const float*)d_in[5];
  const float* b1  = (const float*)d_in[6];
  const float* Wl1 = (const float*)d_in[7];
  const float* bl1 = (const float*)d_in[8];
  const float* Wl2 = (const float*)d_in[9];
  const float* bl2 = (const float*)d_in[10];
  float* out = (float*)d_out;

  // workspace layout (~50.9 MB total)
  char* ws = (char*)d_ws;
  float* deg = (float*)ws;                                       // 512 KB
  unsigned short* Hs = (unsigned short*)(ws + 524288);           // 32 MB
  float* h1 = (float*)(ws + 524288 + 33554432);                  // 16 MB
  float* g  = (float*)(ws + 524288 + 33554432 + 16777216);       // 32 KB

  hipMemsetAsync(g, 0, BB * HC * sizeof(float), stream);
  deg_kernel<<<BB * NN / 4, 256, 0, stream>>>(adj, deg);
  lin_hs_kernel<<<dim3(NN / 16, BB), 256, 0, stream>>>(x, W0, deg, Hs, INC);
  agg_kernel<<<dim3(NN / 64, BB), 256, 0, stream>>>(adj, deg, Hs, b0, msk, h1,
                                                    nullptr, 0);
  lin_hs_kernel<<<dim3(NN / 16, BB), 256, 0, stream>>>(h1, W1, deg, Hs, HC);
  agg_kernel<<<dim3(NN / 64, BB), 256, 0, stream>>>(adj, deg, Hs, b1, msk,
                                                    nullptr, g, 1);
  mlp_kernel<<<BB, HC, 0, stream>>>(g, Wl1, bl1, Wl2, bl2, out);
}